// Round 4
// baseline (348.221 us; speedup 1.0000x reference)
//
#include <hip/hip_runtime.h>
#include <hip/hip_bf16.h>

// EdgeEncoder — fp32 inputs, algebraically folded attention:
//   k[i,j] = kbase[j] + W2k @ hid[i,j],   W2k = Wk @ W2
//   score  = q.kbase[j] + qw[i,hd].hid[i,j]
//   ctx    = sum_j attn*vbase[j] + W2v @ (sum_j attn*hid[i,j])
//
// R4: LDS-pipe relief. KB/VB transposed [s][cw][j] (coalesced setup stores,
// conflict-free S5 reads); wave-uniform constants via scalar loads (feats,
// pos, w1, b1); per-wave values via v_readlane (qw, at); pitch-65/68 LDS.
//
// ws layout (bytes):
//   [0,32K)    W2KT fp32 [e][ckv]  (Wk@W2 transposed)
//   [32K,64K)  W2VT fp32 [e][ckv]
//   [64K,96K)  WQB  u32 [c][mw]    Wq bf16-pairs
//   [96K,128K) OWB  u32 [c][mw]    out_w
//   [128K,192K) PWB u32 [c][mw]    proj_w
//   [192K,+2M) KBt  u32 [s][cw][j] kbase bf16-pairs, j fastest
//   [+2M,+4M)  VBt  u32 [s][cw][j] vbase

typedef unsigned int u32;
#define SCALE 0.17677669529663689f   // 1/sqrt(32)

__device__ __forceinline__ float bl(u32 u){ union{u32 x; float f;} c; c.x = u << 16; return c.f; }
__device__ __forceinline__ float bh(u32 u){ union{u32 x; float f;} c; c.x = u & 0xffff0000u; return c.f; }
__device__ __forceinline__ u32 pk(float a, float b){
  union{float f; u32 x;} ca, cb; ca.f = a; cb.f = b;
  u32 ua = (ca.x + 0x7fffu + ((ca.x >> 16) & 1u)) >> 16;   // RNE fp32->bf16
  u32 ub = (cb.x + 0x7fffu + ((cb.x >> 16) & 1u)) >> 16;
  return ua | (ub << 16);
}
__device__ __forceinline__ float dot8(uint4 u, float4 f0, float4 f1, float acc){
  acc = fmaf(bl(u.x), f0.x, acc); acc = fmaf(bh(u.x), f0.y, acc);
  acc = fmaf(bl(u.y), f0.z, acc); acc = fmaf(bh(u.y), f0.w, acc);
  acc = fmaf(bl(u.z), f1.x, acc); acc = fmaf(bh(u.z), f1.y, acc);
  acc = fmaf(bl(u.w), f1.z, acc); acc = fmaf(bh(u.w), f1.w, acc);
  return acc;
}
__device__ __forceinline__ float rl(float v, int lane){
  return __int_as_float(__builtin_amdgcn_readlane(__float_as_int(v), lane));
}
// wave-local sync: drain LDS ops + compiler scheduling fence.
__device__ __forceinline__ void wsync(){
  __builtin_amdgcn_s_waitcnt(0xC07F);
  __builtin_amdgcn_wave_barrier();
}

// ---------------- kernel 1: bases (transposed) + folds + weight packing ----
// grid 512: b = s*4 + hf*2 + pg.
__global__ __launch_bounds__(256) void ee_setup(
    const float* __restrict__ nf, const float* __restrict__ b2,
    const float* __restrict__ ipw, const float* __restrict__ ipb,
    const float* __restrict__ w2,
    const float* __restrict__ ow, const float* __restrict__ pw,
    float* __restrict__ W2KT, float* __restrict__ W2VT,
    u32* __restrict__ WQB, u32* __restrict__ OWB, u32* __restrict__ PWB,
    u32* __restrict__ KBt, u32* __restrict__ VBt)
{
  __shared__ __align__(16) u32 fbS[64][66];   // (feats+b2) bf16-pairs [j][mw]
  __shared__ __align__(16) u32 wS[64][66];    // Wk-or-Wv half rows [chl][mw]
  __shared__ __align__(16) u32 w2S[128][33];  // W2 bf16 e-pairs [m][ew]
  const int tid = threadIdx.x;
  const int b = blockIdx.x;
  const int s = b >> 2, hf = (b >> 1) & 1, pg = b & 1;
  const float2* nf2  = (const float2*)nf;
  const float2* b22  = (const float2*)b2;
  const float2* ipw2 = (const float2*)ipw;
  const float2* w22  = (const float2*)w2;
  const float2* ow2  = (const float2*)ow;
  const float2* pw2  = (const float2*)pw;

  // independent: pack Wq/out_w/proj_w to bf16 (blocks 384..511), coalesced
  if (b >= 384) {
    int g = (b - 384) * 256 + tid;            // 0..32767
    if (g < 8192) { float2 f = ipw2[g]; WQB[g] = pk(f.x, f.y); }
    else if (g < 16384) { int i = g - 8192; float2 f = ow2[i]; OWB[i] = pk(f.x, f.y); }
    else { int i = g - 16384; float2 f = pw2[i]; PWB[i] = pk(f.x, f.y); }
  }

  for (int idx = tid; idx < 4096; idx += 256) {
    int j = idx >> 6, mw = idx & 63;
    float2 f = nf2[((s << 6) + j) * 64 + mw];
    float2 bb = b22[mw];
    fbS[j][mw] = pk(f.x + bb.x, f.y + bb.y);
  }
  for (int idx = tid; idx < 4096; idx += 256) {
    int chl = idx >> 6, mw = idx & 63;
    float2 wv = ipw2[(128 + hf * 64 + chl) * 64 + mw];   // Wk rows
    wS[chl][mw] = pk(wv.x, wv.y);
  }
  if (s < 16) {
    for (int idx = tid; idx < 4096; idx += 256) {
      int m = idx >> 5, ew = idx & 31;
      float2 wv = w22[m * 32 + ew];
      w2S[m][ew] = pk(wv.x, wv.y);
    }
  }
  __syncthreads();

  const int cg = tid >> 6, lane = tid & 63;
  // kbase quarter -> KBt [s][cw][j]  (coalesced: lane=j contiguous)
  for (int pp = 0; pp < 4; ++pp) {
    int p = pg * 4 + pp;
    int chl = cg * 16 + 2 * p;
    int cw = hf * 32 + cg * 8 + p;
    float a0 = ipb[128 + hf * 64 + chl];
    float a1 = ipb[128 + hf * 64 + chl + 1];
    #pragma unroll 16
    for (int mw = 0; mw < 64; ++mw) {
      u32 fu = fbS[lane][mw];
      u32 w0 = wS[chl][mw], w1v = wS[chl + 1][mw];
      a0 = fmaf(bl(w0), bl(fu), a0); a0 = fmaf(bh(w0), bh(fu), a0);
      a1 = fmaf(bl(w1v), bl(fu), a1); a1 = fmaf(bh(w1v), bh(fu), a1);
    }
    KBt[((s << 6) + cw) * 64 + lane] = pk(a0, a1);
  }
  // W2KT slice (fp32): e = s*4+cg, channels (hf*64+2c, +1), coalesced float2
  if (s < 16 && pg == 0 && lane < 32) {
    int e = s * 4 + cg, c = lane;
    float a0 = 0.f, a1 = 0.f;
    #pragma unroll 16
    for (int mw = 0; mw < 64; ++mw) {
      u32 w0 = wS[2 * c][mw], w1v = wS[2 * c + 1][mw];
      u32 u0 = w2S[2 * mw][e >> 1], u1 = w2S[2 * mw + 1][e >> 1];
      float x0 = (e & 1) ? bh(u0) : bl(u0);
      float x1 = (e & 1) ? bh(u1) : bl(u1);
      a0 = fmaf(bl(w0), x0, a0); a0 = fmaf(bh(w0), x1, a0);
      a1 = fmaf(bl(w1v), x0, a1); a1 = fmaf(bh(w1v), x1, a1);
    }
    ((float2*)W2KT)[e * 64 + hf * 32 + c] = make_float2(a0, a1);
  }
  __syncthreads();
  // restage with Wv
  for (int idx = tid; idx < 4096; idx += 256) {
    int chl = idx >> 6, mw = idx & 63;
    float2 wv = ipw2[(256 + hf * 64 + chl) * 64 + mw];
    wS[chl][mw] = pk(wv.x, wv.y);
  }
  __syncthreads();
  for (int pp = 0; pp < 4; ++pp) {
    int p = pg * 4 + pp;
    int chl = cg * 16 + 2 * p;
    int cw = hf * 32 + cg * 8 + p;
    float a0 = ipb[256 + hf * 64 + chl];
    float a1 = ipb[256 + hf * 64 + chl + 1];
    #pragma unroll 16
    for (int mw = 0; mw < 64; ++mw) {
      u32 fu = fbS[lane][mw];
      u32 w0 = wS[chl][mw], w1v = wS[chl + 1][mw];
      a0 = fmaf(bl(w0), bl(fu), a0); a0 = fmaf(bh(w0), bh(fu), a0);
      a1 = fmaf(bl(w1v), bl(fu), a1); a1 = fmaf(bh(w1v), bh(fu), a1);
    }
    VBt[((s << 6) + cw) * 64 + lane] = pk(a0, a1);
  }
  if (s < 16 && pg == 1 && lane < 32) {
    int e = s * 4 + cg, c = lane;
    float a0 = 0.f, a1 = 0.f;
    #pragma unroll 16
    for (int mw = 0; mw < 64; ++mw) {
      u32 w0 = wS[2 * c][mw], w1v = wS[2 * c + 1][mw];
      u32 u0 = w2S[2 * mw][e >> 1], u1 = w2S[2 * mw + 1][e >> 1];
      float x0 = (e & 1) ? bh(u0) : bl(u0);
      float x1 = (e & 1) ? bh(u1) : bl(u1);
      a0 = fmaf(bl(w0), x0, a0); a0 = fmaf(bh(w0), x1, a0);
      a1 = fmaf(bl(w1v), x0, a1); a1 = fmaf(bh(w1v), x1, a1);
    }
    ((float2*)W2VT)[e * 64 + hf * 32 + c] = make_float2(a0, a1);
  }
}

// ---------------- kernel 2: wave-synchronous fused attention ----------------
// grid 1024 x 512 thr: b = s*8 + oct; wave w -> query il = oct*8 + w.
__global__ __launch_bounds__(512, 4) void ee_main(
    const float* __restrict__ nf, const float* __restrict__ pos,
    const float* __restrict__ w1, const float* __restrict__ b1,
    const float* __restrict__ ipb,
    const float* __restrict__ ob, const float* __restrict__ pb,
    const float* __restrict__ W2KT, const float* __restrict__ W2VT,
    const u32* __restrict__ WQB, const u32* __restrict__ OWB,
    const u32* __restrict__ PWB,
    const u32* __restrict__ KBt, const u32* __restrict__ VBt,
    float* __restrict__ outp)
{
  __shared__ __align__(16) u32 kbS[64][66];      // [cw][j]
  __shared__ __align__(16) u32 vbS[64][66];      // [cw][j]
  __shared__ __align__(16) float2 posS[64];
  __shared__ __align__(16) float2 w1S[64];
  __shared__ __align__(16) float b1S[64];
  __shared__ __align__(16) float qS[8][132];     // q -> ctx -> ao (reused)
  __shared__ __align__(16) float atS[8][4 * 68]; // attn [hd][j], pitch 68
  __shared__ __align__(16) float whS[8][4 * 65]; // wh   [hd][e], pitch 65

  const int tid = threadIdx.x;
  const int s = blockIdx.x >> 3, oct = blockIdx.x & 7;
  const int w = tid >> 6, l = tid & 63;
  const int il = oct * 8 + w;
  const int ig = (s << 6) + il;
  const int c0 = 2 * l;

  {
    const int sb = (s << 6) * 64;
    for (int idx = tid; idx < 4096; idx += 512) kbS[idx >> 6][idx & 63] = KBt[sb + idx];
    for (int idx = tid; idx < 4096; idx += 512) vbS[idx >> 6][idx & 63] = VBt[sb + idx];
    if (tid < 64) {
      posS[tid] = ((const float2*)pos)[(s << 6) + tid];
      w1S[tid]  = ((const float2*)w1)[tid];
      b1S[tid]  = b1[tid];
    }
  }
  __syncthreads();
  // ---- no block barriers past here; each wave runs its query free ----

  // wave-uniform bases for scalar loads
  const float4* fB = (const float4*)nf + __builtin_amdgcn_readfirstlane(ig) * 32;
  const float2* pB = (const float2*)pos + (s << 6);

  // S2: q = Wq @ feats + bq   (lane -> channels 2l, 2l+1)
  {
    float2 bq = ((const float2*)ipb)[l];
    float a0 = bq.x, a1 = bq.y;
    const uint4* W4 = (const uint4*)WQB;
    #pragma unroll 4
    for (int m8 = 0; m8 < 16; ++m8) {
      float4 f0 = fB[2 * m8], f1 = fB[2 * m8 + 1];
      a0 = dot8(W4[c0 * 16 + m8], f0, f1, a0);
      a1 = dot8(W4[(c0 + 1) * 16 + m8], f0, f1, a1);
    }
    *(float2*)&qS[w][c0] = make_float2(a0, a1);
  }
  wsync();

  // S4: qw[hd] (lane = e) from fp32 W2KT (VMEM) + q (LDS b128 broadcast)
  float qw[4];
  {
    const float4* G4 = (const float4*)W2KT;   // [e][128] -> 32 float4/row
    #pragma unroll
    for (int hd = 0; hd < 4; ++hd) {
      float acc = 0.f;
      #pragma unroll
      for (int dq = 0; dq < 8; ++dq) {
        float4 g = G4[l * 32 + hd * 8 + dq];
        float4 qf = *(const float4*)&qS[w][hd * 32 + 4 * dq];
        acc = fmaf(g.x, qf.x, acc); acc = fmaf(g.y, qf.y, acc);
        acc = fmaf(g.z, qf.z, acc); acc = fmaf(g.w, qf.w, acc);
      }
      qw[hd] = acc;
    }
  }

  // S5: scores + softmax (lane = j); qw broadcast via readlane
  float at[4];
  float pix, piy;
  {
    float2 pj = posS[l];
    float2 pi = posS[il];          // same addr all lanes -> broadcast
    pix = pi.x; piy = pi.y;
    float rx = pj.x - pix, ry = pj.y - piy;
    float sc[4];
    #pragma unroll
    for (int hd = 0; hd < 4; ++hd) {
      float a = 0.f;
      #pragma unroll 8
      for (int m = 0; m < 16; ++m) {
        int cw = hd * 16 + m;
        u32 u = kbS[cw][l];                          // conflict-free
        float2 qp = *(const float2*)&qS[w][2 * cw];  // broadcast b64
        a = fmaf(bl(u), qp.x, a); a = fmaf(bh(u), qp.y, a);
      }
      sc[hd] = a;
    }
    #pragma unroll
    for (int eb = 0; eb < 8; ++eb) {
      float h[8];
      #pragma unroll
      for (int m = 0; m < 8; ++m) {
        int e = eb * 8 + m;
        float2 wv = ((const float2*)w1)[e];   // uniform -> scalar load
        float bb = b1[e];                     // uniform -> scalar load
        h[m] = fmaxf(0.f, fmaf(rx, wv.x, fmaf(ry, wv.y, bb)));
      }
      #pragma unroll
      for (int hd = 0; hd < 4; ++hd) {
        float a = sc[hd];
        #pragma unroll
        for (int m = 0; m < 8; ++m) a = fmaf(rl(qw[hd], eb * 8 + m), h[m], a);
        sc[hd] = a;
      }
    }
    #pragma unroll
    for (int hd = 0; hd < 4; ++hd) {
      float v = sc[hd] * SCALE;
      float m = v;
      #pragma unroll
      for (int off = 32; off > 0; off >>= 1) m = fmaxf(m, __shfl_xor(m, off));
      float p = __expf(v - m);
      float su = p;
      #pragma unroll
      for (int off = 32; off > 0; off >>= 1) su += __shfl_xor(su, off);
      at[hd] = p / su;
      atS[w][hd * 68 + l] = at[hd];
    }
  }
  wsync();

  // S6: wh[hd][e] = sum_j at[hd][j]*hid[j][e]  (lane = e; at via readlane,
  // pos via scalar loads)
  {
    float2 wv = w1S[l]; float bb = b1S[l];
    float wh0 = 0.f, wh1 = 0.f, wh2 = 0.f, wh3 = 0.f;
    #pragma unroll 16
    for (int j = 0; j < 64; ++j) {
      float2 pj = pB[j];                       // uniform -> scalar load
      float h = fmaxf(0.f, fmaf(pj.x - pix, wv.x, fmaf(pj.y - piy, wv.y, bb)));
      wh0 = fmaf(rl(at[0], j), h, wh0);
      wh1 = fmaf(rl(at[1], j), h, wh1);
      wh2 = fmaf(rl(at[2], j), h, wh2);
      wh3 = fmaf(rl(at[3], j), h, wh3);
    }
    whS[w][0 * 65 + l] = wh0; whS[w][1 * 65 + l] = wh1;
    whS[w][2 * 65 + l] = wh2; whS[w][3 * 65 + l] = wh3;
  }
  wsync();

  // S7: ctx (lane -> channels 2l,2l+1; head = l>>4)
  float cx0, cx1;
  {
    const int hd = l >> 4;
    float a0 = 0.f, a1 = 0.f;
    const float2* V2 = (const float2*)W2VT;    // [e][128] fp32
    #pragma unroll 8
    for (int e = 0; e < 64; ++e) {
      float wh = whS[w][hd * 65 + e];          // 4 banks, conflict-free
      float2 g = V2[e * 64 + l];               // VMEM coalesced
      a0 = fmaf(wh, g.x, a0); a1 = fmaf(wh, g.y, a1);
    }
    #pragma unroll 8
    for (int j = 0; j < 64; ++j) {
      float a = atS[w][hd * 68 + j];           // 4 banks, conflict-free
      u32 u = vbS[l][j];                       // stride-66: 2-way (free)
      a0 = fmaf(a, bl(u), a0); a1 = fmaf(a, bh(u), a1);
    }
    cx0 = a0; cx1 = a1;
  }
  wsync();
  *(float2*)&qS[w][c0] = make_float2(cx0, cx1);   // ctx overwrites q
  wsync();

  // S8: attn_out = out_w @ ctx + out_b
  float ao0, ao1;
  {
    float2 b = ((const float2*)ob)[l];
    float a0 = b.x, a1 = b.y;
    const uint4* W4 = (const uint4*)OWB;
    #pragma unroll 4
    for (int m8 = 0; m8 < 16; ++m8) {
      float4 f0 = *(const float4*)&qS[w][8 * m8];
      float4 f1 = *(const float4*)&qS[w][8 * m8 + 4];
      a0 = dot8(W4[c0 * 16 + m8], f0, f1, a0);
      a1 = dot8(W4[(c0 + 1) * 16 + m8], f0, f1, a1);
    }
    ao0 = a0; ao1 = a1;
  }
  wsync();
  *(float2*)&qS[w][c0] = make_float2(ao0, ao1);   // ao overwrites ctx
  wsync();

  // S9: out = proj_w @ [feats; attn_out] + proj_b  (fp32 out)
  {
    float2 b = ((const float2*)pb)[l];
    float a0 = b.x, a1 = b.y;
    const uint4* W4 = (const uint4*)PWB;
    #pragma unroll 4
    for (int m8 = 0; m8 < 16; ++m8) {
      float4 f0 = fB[2 * m8], f1 = fB[2 * m8 + 1];   // scalar loads again
      a0 = dot8(W4[c0 * 32 + m8], f0, f1, a0);
      a1 = dot8(W4[(c0 + 1) * 32 + m8], f0, f1, a1);
    }
    #pragma unroll 4
    for (int m8 = 0; m8 < 16; ++m8) {
      float4 f0 = *(const float4*)&qS[w][8 * m8];
      float4 f1 = *(const float4*)&qS[w][8 * m8 + 4];
      a0 = dot8(W4[c0 * 32 + 16 + m8], f0, f1, a0);
      a1 = dot8(W4[(c0 + 1) * 32 + 16 + m8], f0, f1, a1);
    }
    ((float2*)outp)[ig * 64 + l] = make_float2(a0, a1);
  }
}

extern "C" void kernel_launch(void* const* d_in, const int* in_sizes, int n_in,
                              void* d_out, int out_size, void* d_ws, size_t ws_size,
                              hipStream_t stream) {
  (void)in_sizes; (void)n_in; (void)out_size; (void)ws_size;
  const float* nf  = (const float*)d_in[0];
  const float* pos = (const float*)d_in[1];
  const float* w1  = (const float*)d_in[2];
  const float* b1  = (const float*)d_in[3];
  const float* w2  = (const float*)d_in[4];
  const float* b2  = (const float*)d_in[5];
  const float* ipw = (const float*)d_in[6];
  const float* ipb = (const float*)d_in[7];
  const float* ow  = (const float*)d_in[8];
  const float* ob  = (const float*)d_in[9];
  const float* pw  = (const float*)d_in[10];
  const float* pb  = (const float*)d_in[11];

  char* ws = (char*)d_ws;
  float* W2KT = (float*)(ws);
  float* W2VT = (float*)(ws + (32 << 10));
  u32* WQB  = (u32*)(ws + (64 << 10));
  u32* OWB  = (u32*)(ws + (96 << 10));
  u32* PWB  = (u32*)(ws + (128 << 10));
  u32* KBt  = (u32*)(ws + (192 << 10));
  u32* VBt  = (u32*)(ws + (192 << 10) + (128 * 4096 * 4));

  ee_setup<<<dim3(512), dim3(256), 0, stream>>>(nf, b2, ipw, ipb, w2, ow, pw,
                                                W2KT, W2VT, WQB, OWB, PWB, KBt, VBt);
  ee_main<<<dim3(1024), dim3(512), 0, stream>>>(nf, pos, w1, b1, ipb, ob, pb,
                                                W2KT, W2VT, WQB, OWB, PWB,
                                                KBt, VBt, (float*)d_out);
}

// Round 5
// 272.272 us; speedup vs baseline: 1.2789x; 1.2789x over previous
//
#include <hip/hip_runtime.h>
#include <hip/hip_bf16.h>

// EdgeEncoder — fp32 inputs, algebraically folded attention:
//   k[i,j] = kbase[j] + W2k @ hid[i,j],   W2k = Wk @ W2
//   score  = q.kbase[j] + qw[i,hd].hid[i,j]
//   ctx    = sum_j attn*vbase[j] + W2v @ (sum_j attn*hid[i,j])
//
// R5: (a) setup rewritten — weights via scalar (SGPR) loads, feats row in
// registers, zero LDS in the GEMM inner loop; (b) main reads kb/vb straight
// from L1/L2 (no LDS staging -> 4 blocks/CU), SoA tables + fused at/wh
// float2 cut DS-pipe ops ~2x; S6 via constant-index readlane (VALU pipe).
// R4 lesson: no forced-low VGPR + no big live arrays -> no scratch spills.
//
// ws layout (bytes):
//   [0,32K)     W2KT fp32 [e][ch]
//   [32K,64K)   W2VT fp32 [e][ch]
//   [64K,96K)   WQB  u32  [c][mw]   Wq bf16-pairs
//   [96K,128K)  OWB  u32  [c][mw]   out_w
//   [128K,192K) PWB  u32  [c][mw]   proj_w
//   [192K,+2M)  KBt  u32  [s][cw][j]  kbase bf16-pairs, j fastest
//   [+2M,+4M)   VB   u32  [s][j][cw]  vbase, cw fastest

typedef unsigned int u32;
#define SCALE 0.17677669529663689f   // 1/sqrt(32)

__device__ __forceinline__ float bl(u32 u){ union{u32 x; float f;} c; c.x = u << 16; return c.f; }
__device__ __forceinline__ float bh(u32 u){ union{u32 x; float f;} c; c.x = u & 0xffff0000u; return c.f; }
__device__ __forceinline__ u32 pk(float a, float b){
  union{float f; u32 x;} ca, cb; ca.f = a; cb.f = b;
  u32 ua = (ca.x + 0x7fffu + ((ca.x >> 16) & 1u)) >> 16;   // RNE fp32->bf16
  u32 ub = (cb.x + 0x7fffu + ((cb.x >> 16) & 1u)) >> 16;
  return ua | (ub << 16);
}
__device__ __forceinline__ float dot8(uint4 u, float4 f0, float4 f1, float acc){
  acc = fmaf(bl(u.x), f0.x, acc); acc = fmaf(bh(u.x), f0.y, acc);
  acc = fmaf(bl(u.y), f0.z, acc); acc = fmaf(bh(u.y), f0.w, acc);
  acc = fmaf(bl(u.z), f1.x, acc); acc = fmaf(bh(u.z), f1.y, acc);
  acc = fmaf(bl(u.w), f1.z, acc); acc = fmaf(bh(u.w), f1.w, acc);
  return acc;
}
__device__ __forceinline__ float rl(float v, int lane){
  return __int_as_float(__builtin_amdgcn_readlane(__float_as_int(v), lane));
}
__device__ __forceinline__ void wsync(){
  __builtin_amdgcn_s_waitcnt(0xC07F);   // lgkmcnt(0)
  __builtin_amdgcn_wave_barrier();
}

// ---------------- kernel 1: setup -------------------------------------------
// grid 552 x 256:
//   b <  512 : bases.  s=b>>2, kv=(b>>1)&1, hlf=b&1 (64 channels per block)
//   b <  544 : W2 folds. task t=(b-512)*4+wave: kv=t&1, e=t>>1
//   b <  552 : bf16 weight packing (WQB/OWB/PWB)
__global__ __launch_bounds__(256, 2) void ee_setup(
    const float* __restrict__ nf, const float* __restrict__ b2,
    const float* __restrict__ ipw, const float* __restrict__ ipb,
    const float* __restrict__ w2,
    const float* __restrict__ ow, const float* __restrict__ pw,
    float* __restrict__ W2KT, float* __restrict__ W2VT,
    u32* __restrict__ WQB, u32* __restrict__ OWB, u32* __restrict__ PWB,
    u32* __restrict__ KBt, u32* __restrict__ VB)
{
  const int tid = threadIdx.x, b = blockIdx.x;
  const int cg = tid >> 6, l = tid & 63;
  const float2* ipw2 = (const float2*)ipw;
  const float2* ow2  = (const float2*)ow;
  const float2* pw2  = (const float2*)pw;

  if (b >= 544) {              // ---- weight packing, fully coalesced ----
    for (int k = 0; k < 16; ++k) {
      int i = (b - 544) * 4096 + k * 256 + tid;    // 0..32767
      if (i < 8192)       { float2 f = ipw2[i];        WQB[i]        = pk(f.x, f.y); }
      else if (i < 16384) { float2 f = ow2[i - 8192];  OWB[i - 8192] = pk(f.x, f.y); }
      else                { float2 f = pw2[i - 16384]; PWB[i - 16384]= pk(f.x, f.y); }
    }
    return;
  }
  if (b >= 512) {              // ---- W2 folds: W2x[ch][e] = Wk/Wv @ W2 ----
    int t = (b - 512) * 4 + cg;
    int kv = t & 1, e = t >> 1;
    int c0 = 2 * l;
    const float4* rp = (const float4*)ipw + (size_t)(128 + kv * 128 + c0) * 32;
    const float* w2e = w2 + __builtin_amdgcn_readfirstlane(e);
    float a0 = 0.f, a1 = 0.f;
    #pragma unroll 8
    for (int c4 = 0; c4 < 32; ++c4) {
      float4 wa = rp[c4], wb = rp[32 + c4];
      float x0 = w2e[(4 * c4 + 0) * 64];
      float x1 = w2e[(4 * c4 + 1) * 64];
      float x2 = w2e[(4 * c4 + 2) * 64];
      float x3 = w2e[(4 * c4 + 3) * 64];
      a0 = fmaf(wa.x, x0, a0); a0 = fmaf(wa.y, x1, a0);
      a0 = fmaf(wa.z, x2, a0); a0 = fmaf(wa.w, x3, a0);
      a1 = fmaf(wb.x, x0, a1); a1 = fmaf(wb.y, x1, a1);
      a1 = fmaf(wb.z, x2, a1); a1 = fmaf(wb.w, x3, a1);
    }
    float* dst = kv ? W2VT : W2KT;
    ((float2*)dst)[e * 64 + l] = make_float2(a0, a1);
    return;
  }

  // ---- bases: scene s, K-or-V, channel half ----
  const int s = b >> 2, kv = (b >> 1) & 1, hlf = b & 1;
  __shared__ __align__(16) u32 fbS[64][68];   // (feats+b2) bf16-pairs [j][mw]
  __shared__ u32 vtS[64][33];                 // V half-tile [j][c] for transpose
  const float2* nf2 = (const float2*)nf;
  const float2* b22 = (const float2*)b2;

  for (int idx = tid; idx < 4096; idx += 256) {
    int j = idx >> 6, mw = idx & 63;
    float2 f = nf2[((s << 6) + j) * 64 + mw];
    float2 bb = b22[mw];
    fbS[j][mw] = pk(f.x + bb.x, f.y + bb.y);
  }
  __syncthreads();

  // feats row (lane = j) -> 16 uint4 regs, read ONCE
  uint4 fr[16];
  {
    const uint4* frow = (const uint4*)&fbS[l][0];
    #pragma unroll
    for (int k = 0; k < 16; ++k) fr[k] = frow[k];
  }
  #pragma unroll 1
  for (int p = 0; p < 8; ++p) {
    int c0 = hlf * 64 + cg * 16 + 2 * p;               // wave-uniform
    int r0 = 128 + kv * 128 + c0;
    const float4* w0 = (const float4*)ipw +
                       (size_t)__builtin_amdgcn_readfirstlane(r0) * 32;
    const float4* w1r = w0 + 32;
    float a0 = ipb[r0], a1 = ipb[r0 + 1];
    #pragma unroll
    for (int k = 0; k < 16; ++k) {
      uint4 F = fr[k];
      float4 wa = w0[2 * k],  wb = w0[2 * k + 1];
      float4 xa = w1r[2 * k], xb = w1r[2 * k + 1];
      float e0 = bl(F.x), e1 = bh(F.x), e2 = bl(F.y), e3 = bh(F.y);
      float e4 = bl(F.z), e5 = bh(F.z), e6 = bl(F.w), e7 = bh(F.w);
      a0 = fmaf(e0, wa.x, a0); a0 = fmaf(e1, wa.y, a0);
      a0 = fmaf(e2, wa.z, a0); a0 = fmaf(e3, wa.w, a0);
      a0 = fmaf(e4, wb.x, a0); a0 = fmaf(e5, wb.y, a0);
      a0 = fmaf(e6, wb.z, a0); a0 = fmaf(e7, wb.w, a0);
      a1 = fmaf(e0, xa.x, a1); a1 = fmaf(e1, xa.y, a1);
      a1 = fmaf(e2, xa.z, a1); a1 = fmaf(e3, xa.w, a1);
      a1 = fmaf(e4, xb.x, a1); a1 = fmaf(e5, xb.y, a1);
      a1 = fmaf(e6, xb.z, a1); a1 = fmaf(e7, xb.w, a1);
    }
    u32 v = pk(a0, a1);
    int cw = hlf * 32 + cg * 8 + p;
    if (kv == 0) KBt[(((s << 6) + cw) << 6) + l] = v;    // coalesced (lane=j)
    else         vtS[l][cg * 8 + p] = v;                 // transpose via LDS
  }
  if (kv == 1) {
    __syncthreads();
    int r = tid >> 2, cb = (tid & 3) * 8;
    #pragma unroll
    for (int k = 0; k < 8; ++k)
      VB[(((s << 6) + r) << 6) + hlf * 32 + cb + k] = vtS[r][cb + k];
  }
}

// ---------------- kernel 2: wave-synchronous fused attention ----------------
// grid 1024 x 512: b = s*8 + oct; wave w -> query il = oct*8 + w.
__global__ __launch_bounds__(512, 4) void ee_main(
    const float* __restrict__ nf, const float* __restrict__ pos,
    const float* __restrict__ w1, const float* __restrict__ b1,
    const float* __restrict__ ipb,
    const float* __restrict__ ob, const float* __restrict__ pb,
    const float* __restrict__ W2KT, const float* __restrict__ W2VT,
    const u32* __restrict__ WQB, const u32* __restrict__ OWB,
    const u32* __restrict__ PWB,
    const u32* __restrict__ KBt, const u32* __restrict__ VB,
    float* __restrict__ outp)
{
  __shared__ __align__(16) float pxS[64], pyS[64], w1xS[64], w1yS[64], b1S[64];
  __shared__ __align__(16) float fqS[8][132];   // feats[i]
  __shared__ __align__(16) float qS[8][132];    // q -> ctx
  __shared__ __align__(16) float scrS[8][272];  // qw [hd*68+e] -> ao [0..127]
  __shared__ __align__(16) float2 whatS[8][4][66]; // (.x=attn[hd][j], .y=wh[hd][e])

  const int tid = threadIdx.x;
  const int s = blockIdx.x >> 3, oct = blockIdx.x & 7;
  const int w = tid >> 6, l = tid & 63;
  const int il = oct * 8 + w;
  const int ig = (s << 6) + il;
  const int c0 = 2 * l;

  if (tid < 64) {
    float2 p = ((const float2*)pos)[(s << 6) + tid];
    pxS[tid] = p.x; pyS[tid] = p.y;
    float2 wv = ((const float2*)w1)[tid];
    w1xS[tid] = wv.x; w1yS[tid] = wv.y;
    b1S[tid] = b1[tid];
  }
  __syncthreads();
  // ---- no block barriers past here ----

  // S1: feats[i] -> fqS
  *(float2*)&fqS[w][c0] = ((const float2*)nf)[ig * 64 + l];
  wsync();

  // S2: q = Wq @ feats + bq  (lane -> channels c0, c0+1)
  {
    float2 bq = ((const float2*)ipb)[l];
    float a0 = bq.x, a1 = bq.y;
    const uint4* W4 = (const uint4*)WQB;
    #pragma unroll 4
    for (int m8 = 0; m8 < 16; ++m8) {
      float4 f0 = *(const float4*)&fqS[w][8 * m8];
      float4 f1 = *(const float4*)&fqS[w][8 * m8 + 4];
      a0 = dot8(W4[c0 * 16 + m8], f0, f1, a0);
      a1 = dot8(W4[(c0 + 1) * 16 + m8], f0, f1, a1);
    }
    *(float2*)&qS[w][c0] = make_float2(a0, a1);
  }
  wsync();

  // S4: qw[hd][e] = q_hd . W2k[:,e]_hd  (lane = e) -> scrS
  {
    const float4* G4 = (const float4*)W2KT;
    #pragma unroll
    for (int hd = 0; hd < 4; ++hd) {
      float acc = 0.f;
      #pragma unroll
      for (int dq = 0; dq < 8; ++dq) {
        float4 g = G4[l * 32 + hd * 8 + dq];
        float4 qf = *(const float4*)&qS[w][hd * 32 + 4 * dq];
        acc = fmaf(g.x, qf.x, acc); acc = fmaf(g.y, qf.y, acc);
        acc = fmaf(g.z, qf.z, acc); acc = fmaf(g.w, qf.w, acc);
      }
      scrS[w][hd * 68 + l] = acc;
    }
  }
  wsync();

  // S5: scores + softmax  (lane = j; kb from L1/L2 global)
  float at[4];
  float pix, piy;
  {
    float pjx = pxS[l], pjy = pyS[l];
    pix = pxS[il]; piy = pyS[il];          // broadcast
    float rx = pjx - pix, ry = pjy - piy;
    float sc[4];
    #pragma unroll
    for (int hd = 0; hd < 4; ++hd) {
      float a = 0.f;
      #pragma unroll 8
      for (int m = 0; m < 16; ++m) {
        int cw = hd * 16 + m;
        u32 u = KBt[(((s << 6) + cw) << 6) + l];      // coalesced, L1-hot
        float2 qp = *(const float2*)&qS[w][2 * cw];   // broadcast
        a = fmaf(bl(u), qp.x, a); a = fmaf(bh(u), qp.y, a);
      }
      sc[hd] = a;
    }
    #pragma unroll
    for (int eb = 0; eb < 8; ++eb) {
      float4 wx0 = *(const float4*)&w1xS[8 * eb];
      float4 wx1 = *(const float4*)&w1xS[8 * eb + 4];
      float4 wy0 = *(const float4*)&w1yS[8 * eb];
      float4 wy1 = *(const float4*)&w1yS[8 * eb + 4];
      float4 bb0 = *(const float4*)&b1S[8 * eb];
      float4 bb1 = *(const float4*)&b1S[8 * eb + 4];
      float h[8];
      h[0] = fmaxf(0.f, fmaf(rx, wx0.x, fmaf(ry, wy0.x, bb0.x)));
      h[1] = fmaxf(0.f, fmaf(rx, wx0.y, fmaf(ry, wy0.y, bb0.y)));
      h[2] = fmaxf(0.f, fmaf(rx, wx0.z, fmaf(ry, wy0.z, bb0.z)));
      h[3] = fmaxf(0.f, fmaf(rx, wx0.w, fmaf(ry, wy0.w, bb0.w)));
      h[4] = fmaxf(0.f, fmaf(rx, wx1.x, fmaf(ry, wy1.x, bb1.x)));
      h[5] = fmaxf(0.f, fmaf(rx, wx1.y, fmaf(ry, wy1.y, bb1.y)));
      h[6] = fmaxf(0.f, fmaf(rx, wx1.z, fmaf(ry, wy1.z, bb1.z)));
      h[7] = fmaxf(0.f, fmaf(rx, wx1.w, fmaf(ry, wy1.w, bb1.w)));
      #pragma unroll
      for (int hd = 0; hd < 4; ++hd) {
        float4 q0 = *(const float4*)&scrS[w][hd * 68 + 8 * eb];
        float4 q1 = *(const float4*)&scrS[w][hd * 68 + 8 * eb + 4];
        float a = sc[hd];
        a = fmaf(q0.x, h[0], a); a = fmaf(q0.y, h[1], a);
        a = fmaf(q0.z, h[2], a); a = fmaf(q0.w, h[3], a);
        a = fmaf(q1.x, h[4], a); a = fmaf(q1.y, h[5], a);
        a = fmaf(q1.z, h[6], a); a = fmaf(q1.w, h[7], a);
        sc[hd] = a;
      }
    }
    #pragma unroll
    for (int hd = 0; hd < 4; ++hd) {
      float v = sc[hd] * SCALE;
      float m = v;
      #pragma unroll
      for (int off = 32; off > 0; off >>= 1) m = fmaxf(m, __shfl_xor(m, off));
      float p = __expf(v - m);
      float su = p;
      #pragma unroll
      for (int off = 32; off > 0; off >>= 1) su += __shfl_xor(su, off);
      at[hd] = p / su;
      whatS[w][hd][l].x = at[hd];
    }
  }

  // S6: wh[hd][e] (lane = e); attn via constant-lane readlane (VALU pipe)
  {
    float wx = w1xS[l], wy = w1yS[l], bb = b1S[l];
    float wh0 = 0.f, wh1 = 0.f, wh2 = 0.f, wh3 = 0.f;
    #pragma unroll
    for (int j4 = 0; j4 < 16; ++j4) {
      float4 px = *(const float4*)&pxS[4 * j4];
      float4 py = *(const float4*)&pyS[4 * j4];
      #define S6STEP(PX, PY, J) { \
        float h = fmaxf(0.f, fmaf((PX) - pix, wx, fmaf((PY) - piy, wy, bb))); \
        wh0 = fmaf(rl(at[0], (J)), h, wh0); \
        wh1 = fmaf(rl(at[1], (J)), h, wh1); \
        wh2 = fmaf(rl(at[2], (J)), h, wh2); \
        wh3 = fmaf(rl(at[3], (J)), h, wh3); }
      S6STEP(px.x, py.x, 4 * j4 + 0)
      S6STEP(px.y, py.y, 4 * j4 + 1)
      S6STEP(px.z, py.z, 4 * j4 + 2)
      S6STEP(px.w, py.w, 4 * j4 + 3)
      #undef S6STEP
    }
    whatS[w][0][l].y = wh0; whatS[w][1][l].y = wh1;
    whatS[w][2][l].y = wh2; whatS[w][3][l].y = wh3;
  }
  wsync();

  // S7: ctx (lane -> channels c0,c0+1; head = l>>4); single fused n-loop
  {
    const int hd = l >> 4;
    float a0 = 0.f, a1 = 0.f;
    const float2* V2 = (const float2*)W2VT;
    #pragma unroll 8
    for (int n = 0; n < 64; ++n) {
      float2 aw = whatS[w][hd][n];               // conflict-free b64
      float2 g = V2[n * 64 + l];                 // coalesced (L2)
      u32 vb = VB[(((s << 6) + n) << 6) + l];    // coalesced (L1-hot)
      a0 = fmaf(aw.y, g.x, a0); a1 = fmaf(aw.y, g.y, a1);
      a0 = fmaf(aw.x, bl(vb), a0); a1 = fmaf(aw.x, bh(vb), a1);
    }
    wsync();                                     // qS(q) last read in S5
    *(float2*)&qS[w][c0] = make_float2(a0, a1);  // ctx overwrites q
  }
  wsync();

  // S8: attn_out = out_w @ ctx + out_b -> scrS[0..127] (qw dead)
  {
    float2 b = ((const float2*)ob)[l];
    float a0 = b.x, a1 = b.y;
    const uint4* W4 = (const uint4*)OWB;
    #pragma unroll 4
    for (int m8 = 0; m8 < 16; ++m8) {
      float4 f0 = *(const float4*)&qS[w][8 * m8];
      float4 f1 = *(const float4*)&qS[w][8 * m8 + 4];
      a0 = dot8(W4[c0 * 16 + m8], f0, f1, a0);
      a1 = dot8(W4[(c0 + 1) * 16 + m8], f0, f1, a1);
    }
    *(float2*)&scrS[w][c0] = make_float2(a0, a1);
  }
  wsync();

  // S9: out = proj_w @ [feats; attn_out] + proj_b  (fp32 out)
  {
    float2 b = ((const float2*)pb)[l];
    float a0 = b.x, a1 = b.y;
    const uint4* W4 = (const uint4*)PWB;
    #pragma unroll 4
    for (int m8 = 0; m8 < 16; ++m8) {
      float4 f0 = *(const float4*)&fqS[w][8 * m8];
      float4 f1 = *(const float4*)&fqS[w][8 * m8 + 4];
      a0 = dot8(W4[c0 * 32 + m8], f0, f1, a0);
      a1 = dot8(W4[(c0 + 1) * 32 + m8], f0, f1, a1);
    }
    #pragma unroll 4
    for (int m8 = 0; m8 < 16; ++m8) {
      float4 f0 = *(const float4*)&scrS[w][8 * m8];
      float4 f1 = *(const float4*)&scrS[w][8 * m8 + 4];
      a0 = dot8(W4[c0 * 32 + 16 + m8], f0, f1, a0);
      a1 = dot8(W4[(c0 + 1) * 32 + 16 + m8], f0, f1, a1);
    }
    ((float2*)outp)[ig * 64 + l] = make_float2(a0, a1);
  }
}

extern "C" void kernel_launch(void* const* d_in, const int* in_sizes, int n_in,
                              void* d_out, int out_size, void* d_ws, size_t ws_size,
                              hipStream_t stream) {
  (void)in_sizes; (void)n_in; (void)out_size; (void)ws_size;
  const float* nf  = (const float*)d_in[0];
  const float* pos = (const float*)d_in[1];
  const float* w1  = (const float*)d_in[2];
  const float* b1  = (const float*)d_in[3];
  const float* w2  = (const float*)d_in[4];
  const float* b2  = (const float*)d_in[5];
  const float* ipw = (const float*)d_in[6];
  const float* ipb = (const float*)d_in[7];
  const float* ow  = (const float*)d_in[8];
  const float* ob  = (const float*)d_in[9];
  const float* pw  = (const float*)d_in[10];
  const float* pb  = (const float*)d_in[11];

  char* ws = (char*)d_ws;
  float* W2KT = (float*)(ws);
  float* W2VT = (float*)(ws + (32 << 10));
  u32* WQB  = (u32*)(ws + (64 << 10));
  u32* OWB  = (u32*)(ws + (96 << 10));
  u32* PWB  = (u32*)(ws + (128 << 10));
  u32* KBt  = (u32*)(ws + (192 << 10));
  u32* VB   = (u32*)(ws + (192 << 10) + (128 * 4096 * 4));

  ee_setup<<<dim3(552), dim3(256), 0, stream>>>(nf, b2, ipw, ipb, w2, ow, pw,
                                                W2KT, W2VT, WQB, OWB, PWB, KBt, VB);
  ee_main<<<dim3(1024), dim3(512), 0, stream>>>(nf, pos, w1, b1, ipb, ob, pb,
                                                W2KT, W2VT, WQB, OWB, PWB,
                                                KBt, VB, (float*)d_out);
}

// Round 7
// 174.512 us; speedup vs baseline: 1.9954x; 1.5602x over previous
//
#include <hip/hip_runtime.h>
#include <hip/hip_bf16.h>

// EdgeEncoder — fp32 inputs, algebraically folded attention:
//   k[i,j] = kbase[j] + W2k @ hid[i,j],   W2k = Wk @ W2
//   score  = q.kbase[j] + qw[i,hd].hid[i,j]
//   ctx    = sum_j attn*vbase[j] + W2v @ (sum_j attn*hid[i,j])
//
// R7 = R6 resubmit (R6 bench died in harness infra, no kernel verdict):
// ee_main processes Q=4 queries per wave (interleaved), amortizing every
// weight/kbase/vbase load x4 and giving 4 independent FMA chains of ILP.
// 512 blocks x 256 thr, ~69KB LDS -> 2 blocks/CU. Wave-synchronous (no
// block barriers after init). total-main gap ~85us is harness reset
// overhead (constant across R2-R5) — not addressable in-kernel.
//
// ws layout (bytes):
//   [0,32K)     W2KT fp32 [e][ch]
//   [32K,64K)   W2VT fp32 [e][ch]
//   [64K,96K)   WQB  u32  [c][mw]   Wq bf16-pairs
//   [96K,128K)  OWB  u32  [c][mw]   out_w
//   [128K,192K) PWB  u32  [c][mw]   proj_w
//   [192K,+2M)  KBt  u32  [s][cw][j]  kbase bf16-pairs, j fastest
//   [+2M,+4M)   VB   u32  [s][j][cw]  vbase, cw fastest

typedef unsigned int u32;
#define SCALE 0.17677669529663689f   // 1/sqrt(32)

__device__ __forceinline__ float bl(u32 u){ union{u32 x; float f;} c; c.x = u << 16; return c.f; }
__device__ __forceinline__ float bh(u32 u){ union{u32 x; float f;} c; c.x = u & 0xffff0000u; return c.f; }
__device__ __forceinline__ u32 pk(float a, float b){
  union{float f; u32 x;} ca, cb; ca.f = a; cb.f = b;
  u32 ua = (ca.x + 0x7fffu + ((ca.x >> 16) & 1u)) >> 16;   // RNE fp32->bf16
  u32 ub = (cb.x + 0x7fffu + ((cb.x >> 16) & 1u)) >> 16;
  return ua | (ub << 16);
}
__device__ __forceinline__ float dot8(uint4 u, float4 f0, float4 f1, float acc){
  acc = fmaf(bl(u.x), f0.x, acc); acc = fmaf(bh(u.x), f0.y, acc);
  acc = fmaf(bl(u.y), f0.z, acc); acc = fmaf(bh(u.y), f0.w, acc);
  acc = fmaf(bl(u.z), f1.x, acc); acc = fmaf(bh(u.z), f1.y, acc);
  acc = fmaf(bl(u.w), f1.z, acc); acc = fmaf(bh(u.w), f1.w, acc);
  return acc;
}
__device__ __forceinline__ void wsync(){
  __builtin_amdgcn_s_waitcnt(0xC07F);   // lgkmcnt(0)
  __builtin_amdgcn_wave_barrier();
}

// ---------------- kernel 1: setup (R5-proven) -------------------------------
__global__ __launch_bounds__(256, 2) void ee_setup(
    const float* __restrict__ nf, const float* __restrict__ b2,
    const float* __restrict__ ipw, const float* __restrict__ ipb,
    const float* __restrict__ w2,
    const float* __restrict__ ow, const float* __restrict__ pw,
    float* __restrict__ W2KT, float* __restrict__ W2VT,
    u32* __restrict__ WQB, u32* __restrict__ OWB, u32* __restrict__ PWB,
    u32* __restrict__ KBt, u32* __restrict__ VB)
{
  const int tid = threadIdx.x, b = blockIdx.x;
  const int cg = tid >> 6, l = tid & 63;
  const float2* ipw2 = (const float2*)ipw;
  const float2* ow2  = (const float2*)ow;
  const float2* pw2  = (const float2*)pw;

  if (b >= 544) {              // ---- weight packing, fully coalesced ----
    for (int k = 0; k < 16; ++k) {
      int i = (b - 544) * 4096 + k * 256 + tid;    // 0..32767
      if (i < 8192)       { float2 f = ipw2[i];        WQB[i]        = pk(f.x, f.y); }
      else if (i < 16384) { float2 f = ow2[i - 8192];  OWB[i - 8192] = pk(f.x, f.y); }
      else                { float2 f = pw2[i - 16384]; PWB[i - 16384]= pk(f.x, f.y); }
    }
    return;
  }
  if (b >= 512) {              // ---- W2 folds: W2x[ch][e] = Wk/Wv @ W2 ----
    int t = (b - 512) * 4 + cg;
    int kv = t & 1, e = t >> 1;
    int c0 = 2 * l;
    const float4* rp = (const float4*)ipw + (size_t)(128 + kv * 128 + c0) * 32;
    const float* w2e = w2 + __builtin_amdgcn_readfirstlane(e);
    float a0 = 0.f, a1 = 0.f;
    #pragma unroll 8
    for (int c4 = 0; c4 < 32; ++c4) {
      float4 wa = rp[c4], wb = rp[32 + c4];
      float x0 = w2e[(4 * c4 + 0) * 64];
      float x1 = w2e[(4 * c4 + 1) * 64];
      float x2 = w2e[(4 * c4 + 2) * 64];
      float x3 = w2e[(4 * c4 + 3) * 64];
      a0 = fmaf(wa.x, x0, a0); a0 = fmaf(wa.y, x1, a0);
      a0 = fmaf(wa.z, x2, a0); a0 = fmaf(wa.w, x3, a0);
      a1 = fmaf(wb.x, x0, a1); a1 = fmaf(wb.y, x1, a1);
      a1 = fmaf(wb.z, x2, a1); a1 = fmaf(wb.w, x3, a1);
    }
    float* dst = kv ? W2VT : W2KT;
    ((float2*)dst)[e * 64 + l] = make_float2(a0, a1);
    return;
  }

  const int s = b >> 2, kv = (b >> 1) & 1, hlf = b & 1;
  __shared__ __align__(16) u32 fbS[64][68];
  __shared__ u32 vtS[64][33];
  const float2* nf2 = (const float2*)nf;
  const float2* b22 = (const float2*)b2;

  for (int idx = tid; idx < 4096; idx += 256) {
    int j = idx >> 6, mw = idx & 63;
    float2 f = nf2[((s << 6) + j) * 64 + mw];
    float2 bb = b22[mw];
    fbS[j][mw] = pk(f.x + bb.x, f.y + bb.y);
  }
  __syncthreads();

  uint4 fr[16];
  {
    const uint4* frow = (const uint4*)&fbS[l][0];
    #pragma unroll
    for (int k = 0; k < 16; ++k) fr[k] = frow[k];
  }
  #pragma unroll 1
  for (int p = 0; p < 8; ++p) {
    int c0 = hlf * 64 + cg * 16 + 2 * p;
    int r0 = 128 + kv * 128 + c0;
    const float4* w0 = (const float4*)ipw +
                       (size_t)__builtin_amdgcn_readfirstlane(r0) * 32;
    const float4* w1r = w0 + 32;
    float a0 = ipb[r0], a1 = ipb[r0 + 1];
    #pragma unroll
    for (int k = 0; k < 16; ++k) {
      uint4 F = fr[k];
      float4 wa = w0[2 * k],  wb = w0[2 * k + 1];
      float4 xa = w1r[2 * k], xb = w1r[2 * k + 1];
      float e0 = bl(F.x), e1 = bh(F.x), e2 = bl(F.y), e3 = bh(F.y);
      float e4 = bl(F.z), e5 = bh(F.z), e6 = bl(F.w), e7 = bh(F.w);
      a0 = fmaf(e0, wa.x, a0); a0 = fmaf(e1, wa.y, a0);
      a0 = fmaf(e2, wa.z, a0); a0 = fmaf(e3, wa.w, a0);
      a0 = fmaf(e4, wb.x, a0); a0 = fmaf(e5, wb.y, a0);
      a0 = fmaf(e6, wb.z, a0); a0 = fmaf(e7, wb.w, a0);
      a1 = fmaf(e0, xa.x, a1); a1 = fmaf(e1, xa.y, a1);
      a1 = fmaf(e2, xa.z, a1); a1 = fmaf(e3, xa.w, a1);
      a1 = fmaf(e4, xb.x, a1); a1 = fmaf(e5, xb.y, a1);
      a1 = fmaf(e6, xb.z, a1); a1 = fmaf(e7, xb.w, a1);
    }
    u32 v = pk(a0, a1);
    int cw = hlf * 32 + cg * 8 + p;
    if (kv == 0) KBt[(((s << 6) + cw) << 6) + l] = v;
    else         vtS[l][cg * 8 + p] = v;
  }
  if (kv == 1) {
    __syncthreads();
    int r = tid >> 2, cb = (tid & 3) * 8;
    #pragma unroll
    for (int k = 0; k < 8; ++k)
      VB[(((s << 6) + r) << 6) + hlf * 32 + cb + k] = vtS[r][cb + k];
  }
}

// ---------------- kernel 2: Q=4 queries per wave, wave-synchronous ----------
// grid 512 x 256: b -> s = b>>2, qt = b&3; wave w -> queries qt*16+4w+t.
__global__ __launch_bounds__(256, 2) void ee_main(
    const float* __restrict__ nf, const float* __restrict__ pos,
    const float* __restrict__ w1, const float* __restrict__ b1,
    const float* __restrict__ ipb,
    const float* __restrict__ ob, const float* __restrict__ pb,
    const float* __restrict__ W2KT, const float* __restrict__ W2VT,
    const u32* __restrict__ WQB, const u32* __restrict__ OWB,
    const u32* __restrict__ PWB,
    const u32* __restrict__ KBt, const u32* __restrict__ VB,
    float* __restrict__ outp)
{
  __shared__ __align__(16) float pxS[64], pyS[64], w1xS[64], w1yS[64], b1S[64];
  __shared__ __align__(16) float fqS[4][4][132];     // feats  [w][t][c]
  __shared__ __align__(16) float qS [4][4][132];     // q -> ctx
  __shared__ __align__(16) float qwS[4][4][4][68];   // qw [w][t][hd][e]
  __shared__ __align__(16) float atS[4][4][4][68];   // at [w][t][hd][j]
  __shared__ __align__(16) float whS[4][4][4][68];   // wh [w][t][hd][e] -> ao

  const int tid = threadIdx.x;
  const int s = blockIdx.x >> 2, qt = blockIdx.x & 3;
  const int w = tid >> 6, l = tid & 63;
  const int c0 = 2 * l;

  if (tid < 64) {
    float2 p = ((const float2*)pos)[(s << 6) + tid];
    pxS[tid] = p.x; pyS[tid] = p.y;
    float2 wv = ((const float2*)w1)[tid];
    w1xS[tid] = wv.x; w1yS[tid] = wv.y;
    b1S[tid] = b1[tid];
  }
  __syncthreads();
  // ---- no block barriers past here ----

  int il[4], ig[4];
  #pragma unroll
  for (int t = 0; t < 4; ++t) { il[t] = qt * 16 + 4 * w + t; ig[t] = (s << 6) + il[t]; }

  // S1: feats for 4 queries -> LDS
  #pragma unroll
  for (int t = 0; t < 4; ++t)
    *(float2*)&fqS[w][t][c0] = ((const float2*)nf)[ig[t] * 64 + l];
  wsync();

  // S2: q = Wq @ feats + bq  (lane -> channels c0,c0+1; weights reused x4)
  {
    float2 bq = ((const float2*)ipb)[l];
    float a0[4], a1[4];
    #pragma unroll
    for (int t = 0; t < 4; ++t) { a0[t] = bq.x; a1[t] = bq.y; }
    const uint4* W4 = (const uint4*)WQB;
    #pragma unroll 4
    for (int m8 = 0; m8 < 16; ++m8) {
      uint4 ua = W4[c0 * 16 + m8];
      uint4 ub = W4[(c0 + 1) * 16 + m8];
      #pragma unroll
      for (int t = 0; t < 4; ++t) {
        float4 f0 = *(const float4*)&fqS[w][t][8 * m8];
        float4 f1 = *(const float4*)&fqS[w][t][8 * m8 + 4];
        a0[t] = dot8(ua, f0, f1, a0[t]);
        a1[t] = dot8(ub, f0, f1, a1[t]);
      }
    }
    #pragma unroll
    for (int t = 0; t < 4; ++t)
      *(float2*)&qS[w][t][c0] = make_float2(a0[t], a1[t]);
  }
  wsync();

  // S4: qw[t][hd][e=l] = q_hd . W2k[:,e]_hd  (W2KT rows reused x4)
  {
    const float4* G4 = (const float4*)W2KT;
    #pragma unroll
    for (int hd = 0; hd < 4; ++hd) {
      float acc[4] = {0.f, 0.f, 0.f, 0.f};
      #pragma unroll
      for (int dq = 0; dq < 8; ++dq) {
        float4 g = G4[l * 32 + hd * 8 + dq];
        #pragma unroll
        for (int t = 0; t < 4; ++t) {
          float4 qf = *(const float4*)&qS[w][t][hd * 32 + 4 * dq];
          acc[t] = fmaf(g.x, qf.x, acc[t]); acc[t] = fmaf(g.y, qf.y, acc[t]);
          acc[t] = fmaf(g.z, qf.z, acc[t]); acc[t] = fmaf(g.w, qf.w, acc[t]);
        }
      }
      #pragma unroll
      for (int t = 0; t < 4; ++t) qwS[w][t][hd][l] = acc[t];
    }
  }
  wsync();

  // S5: scores + softmax (lane = j; kb loads reused x4)
  float at[4][4];        // [t][hd]
  float pix[4], piy[4];
  {
    float pjx = pxS[l], pjy = pyS[l];
    float rx[4], ry[4];
    #pragma unroll
    for (int t = 0; t < 4; ++t) {
      pix[t] = pxS[il[t]]; piy[t] = pyS[il[t]];      // broadcast reads
      rx[t] = pjx - pix[t]; ry[t] = pjy - piy[t];
    }
    float sc[4][4];
    #pragma unroll
    for (int t = 0; t < 4; ++t)
      #pragma unroll
      for (int hd = 0; hd < 4; ++hd) sc[t][hd] = 0.f;

    const u32* kbp = KBt + (s << 12);
    #pragma unroll 8
    for (int m2 = 0; m2 < 32; ++m2) {
      u32 u0 = kbp[((2 * m2) << 6) + l];
      u32 u1 = kbp[((2 * m2 + 1) << 6) + l];
      const int hd = m2 >> 3;
      #pragma unroll
      for (int t = 0; t < 4; ++t) {
        float4 qf = *(const float4*)&qS[w][t][4 * m2];
        sc[t][hd] = fmaf(bl(u0), qf.x, sc[t][hd]);
        sc[t][hd] = fmaf(bh(u0), qf.y, sc[t][hd]);
        sc[t][hd] = fmaf(bl(u1), qf.z, sc[t][hd]);
        sc[t][hd] = fmaf(bh(u1), qf.w, sc[t][hd]);
      }
    }
    #pragma unroll 2
    for (int eb = 0; eb < 8; ++eb) {
      float4 wx0 = *(const float4*)&w1xS[8 * eb];
      float4 wx1 = *(const float4*)&w1xS[8 * eb + 4];
      float4 wy0 = *(const float4*)&w1yS[8 * eb];
      float4 wy1 = *(const float4*)&w1yS[8 * eb + 4];
      float4 bb0 = *(const float4*)&b1S[8 * eb];
      float4 bb1 = *(const float4*)&b1S[8 * eb + 4];
      #pragma unroll
      for (int t = 0; t < 4; ++t) {
        float h0 = fmaxf(0.f, fmaf(rx[t], wx0.x, fmaf(ry[t], wy0.x, bb0.x)));
        float h1 = fmaxf(0.f, fmaf(rx[t], wx0.y, fmaf(ry[t], wy0.y, bb0.y)));
        float h2 = fmaxf(0.f, fmaf(rx[t], wx0.z, fmaf(ry[t], wy0.z, bb0.z)));
        float h3 = fmaxf(0.f, fmaf(rx[t], wx0.w, fmaf(ry[t], wy0.w, bb0.w)));
        float h4 = fmaxf(0.f, fmaf(rx[t], wx1.x, fmaf(ry[t], wy1.x, bb1.x)));
        float h5 = fmaxf(0.f, fmaf(rx[t], wx1.y, fmaf(ry[t], wy1.y, bb1.y)));
        float h6 = fmaxf(0.f, fmaf(rx[t], wx1.z, fmaf(ry[t], wy1.z, bb1.z)));
        float h7 = fmaxf(0.f, fmaf(rx[t], wx1.w, fmaf(ry[t], wy1.w, bb1.w)));
        #pragma unroll
        for (int hd = 0; hd < 4; ++hd) {
          float4 q0 = *(const float4*)&qwS[w][t][hd][8 * eb];
          float4 q1 = *(const float4*)&qwS[w][t][hd][8 * eb + 4];
          float a = sc[t][hd];
          a = fmaf(q0.x, h0, a); a = fmaf(q0.y, h1, a);
          a = fmaf(q0.z, h2, a); a = fmaf(q0.w, h3, a);
          a = fmaf(q1.x, h4, a); a = fmaf(q1.y, h5, a);
          a = fmaf(q1.z, h6, a); a = fmaf(q1.w, h7, a);
          sc[t][hd] = a;
        }
      }
    }
    #pragma unroll
    for (int t = 0; t < 4; ++t) {
      #pragma unroll
      for (int hd = 0; hd < 4; ++hd) {
        float v = sc[t][hd] * SCALE;
        float m = v;
        #pragma unroll
        for (int off = 32; off > 0; off >>= 1) m = fmaxf(m, __shfl_xor(m, off));
        float p = __expf(v - m);
        float su = p;
        #pragma unroll
        for (int off = 32; off > 0; off >>= 1) su += __shfl_xor(su, off);
#if __has_builtin(__builtin_amdgcn_rcpf)
        at[t][hd] = p * __builtin_amdgcn_rcpf(su);
#else
        at[t][hd] = p / su;
#endif
        atS[w][t][hd][l] = at[t][hd];
      }
    }
  }
  wsync();

  // S6: wh[t][hd][e=l] = sum_j at[t][hd][j]*hid[t][j][e]  (at via LDS b128)
  {
    float wx = w1xS[l], wy = w1yS[l], bb = b1S[l];
    float wh[4][4];
    #pragma unroll
    for (int t = 0; t < 4; ++t)
      #pragma unroll
      for (int hd = 0; hd < 4; ++hd) wh[t][hd] = 0.f;
    #pragma unroll 4
    for (int j4 = 0; j4 < 16; ++j4) {
      float4 px = *(const float4*)&pxS[4 * j4];
      float4 py = *(const float4*)&pyS[4 * j4];
      #pragma unroll
      for (int t = 0; t < 4; ++t) {
        float4 a0v = *(const float4*)&atS[w][t][0][4 * j4];
        float4 a1v = *(const float4*)&atS[w][t][1][4 * j4];
        float4 a2v = *(const float4*)&atS[w][t][2][4 * j4];
        float4 a3v = *(const float4*)&atS[w][t][3][4 * j4];
        float h;
        h = fmaxf(0.f, fmaf(px.x - pix[t], wx, fmaf(py.x - piy[t], wy, bb)));
        wh[t][0] = fmaf(a0v.x, h, wh[t][0]); wh[t][1] = fmaf(a1v.x, h, wh[t][1]);
        wh[t][2] = fmaf(a2v.x, h, wh[t][2]); wh[t][3] = fmaf(a3v.x, h, wh[t][3]);
        h = fmaxf(0.f, fmaf(px.y - pix[t], wx, fmaf(py.y - piy[t], wy, bb)));
        wh[t][0] = fmaf(a0v.y, h, wh[t][0]); wh[t][1] = fmaf(a1v.y, h, wh[t][1]);
        wh[t][2] = fmaf(a2v.y, h, wh[t][2]); wh[t][3] = fmaf(a3v.y, h, wh[t][3]);
        h = fmaxf(0.f, fmaf(px.z - pix[t], wx, fmaf(py.z - piy[t], wy, bb)));
        wh[t][0] = fmaf(a0v.z, h, wh[t][0]); wh[t][1] = fmaf(a1v.z, h, wh[t][1]);
        wh[t][2] = fmaf(a2v.z, h, wh[t][2]); wh[t][3] = fmaf(a3v.z, h, wh[t][3]);
        h = fmaxf(0.f, fmaf(px.w - pix[t], wx, fmaf(py.w - piy[t], wy, bb)));
        wh[t][0] = fmaf(a0v.w, h, wh[t][0]); wh[t][1] = fmaf(a1v.w, h, wh[t][1]);
        wh[t][2] = fmaf(a2v.w, h, wh[t][2]); wh[t][3] = fmaf(a3v.w, h, wh[t][3]);
      }
    }
    #pragma unroll
    for (int t = 0; t < 4; ++t)
      #pragma unroll
      for (int hd = 0; hd < 4; ++hd) whS[w][t][hd][l] = wh[t][hd];
  }
  wsync();

  // S7: ctx (lane -> channels c0,c0+1; head = l>>4); vb/W2VT reused x4
  {
    const int hd = l >> 4;
    float cx0[4] = {0,0,0,0}, cx1[4] = {0,0,0,0};
    const float2* V2 = (const float2*)W2VT;
    const u32* vbp = VB + (s << 12);
    #pragma unroll 4
    for (int n4 = 0; n4 < 16; ++n4) {
      float2 g0 = V2[((4 * n4 + 0) << 6) + l];
      float2 g1 = V2[((4 * n4 + 1) << 6) + l];
      float2 g2 = V2[((4 * n4 + 2) << 6) + l];
      float2 g3 = V2[((4 * n4 + 3) << 6) + l];
      u32 v0 = vbp[((4 * n4 + 0) << 6) + l];
      u32 v1 = vbp[((4 * n4 + 1) << 6) + l];
      u32 v2 = vbp[((4 * n4 + 2) << 6) + l];
      u32 v3 = vbp[((4 * n4 + 3) << 6) + l];
      #pragma unroll
      for (int t = 0; t < 4; ++t) {
        float4 whv = *(const float4*)&whS[w][t][hd][4 * n4];
        float4 atv = *(const float4*)&atS[w][t][hd][4 * n4];
        float a0 = cx0[t], a1 = cx1[t];
        a0 = fmaf(whv.x, g0.x, a0); a1 = fmaf(whv.x, g0.y, a1);
        a0 = fmaf(atv.x, bl(v0), a0); a1 = fmaf(atv.x, bh(v0), a1);
        a0 = fmaf(whv.y, g1.x, a0); a1 = fmaf(whv.y, g1.y, a1);
        a0 = fmaf(atv.y, bl(v1), a0); a1 = fmaf(atv.y, bh(v1), a1);
        a0 = fmaf(whv.z, g2.x, a0); a1 = fmaf(whv.z, g2.y, a1);
        a0 = fmaf(atv.z, bl(v2), a0); a1 = fmaf(atv.z, bh(v2), a1);
        a0 = fmaf(whv.w, g3.x, a0); a1 = fmaf(whv.w, g3.y, a1);
        a0 = fmaf(atv.w, bl(v3), a0); a1 = fmaf(atv.w, bh(v3), a1);
        cx0[t] = a0; cx1[t] = a1;
      }
    }
    wsync();
    #pragma unroll
    for (int t = 0; t < 4; ++t)
      *(float2*)&qS[w][t][c0] = make_float2(cx0[t], cx1[t]);   // ctx over q
  }
  wsync();

  // S8: attn_out = out_w @ ctx + out_b   (-> whS region, flat per t)
  {
    float2 b = ((const float2*)ob)[l];
    float a0[4], a1[4];
    #pragma unroll
    for (int t = 0; t < 4; ++t) { a0[t] = b.x; a1[t] = b.y; }
    const uint4* W4 = (const uint4*)OWB;
    #pragma unroll 4
    for (int m8 = 0; m8 < 16; ++m8) {
      uint4 ua = W4[c0 * 16 + m8];
      uint4 ub = W4[(c0 + 1) * 16 + m8];
      #pragma unroll
      for (int t = 0; t < 4; ++t) {
        float4 f0 = *(const float4*)&qS[w][t][8 * m8];
        float4 f1 = *(const float4*)&qS[w][t][8 * m8 + 4];
        a0[t] = dot8(ua, f0, f1, a0[t]);
        a1[t] = dot8(ub, f0, f1, a1[t]);
      }
    }
    wsync();   // whS (wh) reads in S7 complete before overwrite
    #pragma unroll
    for (int t = 0; t < 4; ++t)
      *(float2*)(&whS[w][t][0][0] + c0) = make_float2(a0[t], a1[t]);
  }
  wsync();

  // S9: out = proj_w @ [feats; attn_out] + proj_b  (fp32 out)
  {
    float2 b = ((const float2*)pb)[l];
    float a0[4], a1[4];
    #pragma unroll
    for (int t = 0; t < 4; ++t) { a0[t] = b.x; a1[t] = b.y; }
    const uint4* W4 = (const uint4*)PWB;
    #pragma unroll 2
    for (int m8 = 0; m8 < 16; ++m8) {
      uint4 ua = W4[c0 * 32 + m8];
      uint4 ub = W4[(c0 + 1) * 32 + m8];
      uint4 uc = W4[c0 * 32 + 16 + m8];
      uint4 ud = W4[(c0 + 1) * 32 + 16 + m8];
      #pragma unroll
      for (int t = 0; t < 4; ++t) {
        float4 f0 = *(const float4*)&fqS[w][t][8 * m8];
        float4 f1 = *(const float4*)&fqS[w][t][8 * m8 + 4];
        float4 g0 = *(const float4*)(&whS[w][t][0][0] + 8 * m8);
        float4 g1 = *(const float4*)(&whS[w][t][0][0] + 8 * m8 + 4);
        a0[t] = dot8(ua, f0, f1, a0[t]);
        a1[t] = dot8(ub, f0, f1, a1[t]);
        a0[t] = dot8(uc, g0, g1, a0[t]);
        a1[t] = dot8(ud, g0, g1, a1[t]);
      }
    }
    #pragma unroll
    for (int t = 0; t < 4; ++t)
      ((float2*)outp)[ig[t] * 64 + l] = make_float2(a0[t], a1[t]);
  }
}

extern "C" void kernel_launch(void* const* d_in, const int* in_sizes, int n_in,
                              void* d_out, int out_size, void* d_ws, size_t ws_size,
                              hipStream_t stream) {
  (void)in_sizes; (void)n_in; (void)out_size; (void)ws_size;
  const float* nf  = (const float*)d_in[0];
  const float* pos = (const float*)d_in[1];
  const float* w1  = (const float*)d_in[2];
  const float* b1  = (const float*)d_in[3];
  const float* w2  = (const float*)d_in[4];
  const float* b2  = (const float*)d_in[5];
  const float* ipw = (const float*)d_in[6];
  const float* ipb = (const float*)d_in[7];
  const float* ow  = (const float*)d_in[8];
  const float* ob  = (const float*)d_in[9];
  const float* pw  = (const float*)d_in[10];
  const float* pb  = (const float*)d_in[11];

  char* ws = (char*)d_ws;
  float* W2KT = (float*)(ws);
  float* W2VT = (float*)(ws + (32 << 10));
  u32* WQB  = (u32*)(ws + (64 << 10));
  u32* OWB  = (u32*)(ws + (96 << 10));
  u32* PWB  = (u32*)(ws + (128 << 10));
  u32* KBt  = (u32*)(ws + (192 << 10));
  u32* VB   = (u32*)(ws + (192 << 10) + (128 * 4096 * 4));

  ee_setup<<<dim3(552), dim3(256), 0, stream>>>(nf, b2, ipw, ipb, w2, ow, pw,
                                                W2KT, W2VT, WQB, OWB, PWB, KBt, VB);
  ee_main<<<dim3(512), dim3(256), 0, stream>>>(nf, pos, w1, b1, ipb, ob, pb,
                                               W2KT, W2VT, WQB, OWB, PWB,
                                               KBt, VB, (float*)d_out);
}